// Round 4
// baseline (622.110 us; speedup 1.0000x reference)
//
#include <hip/hip_runtime.h>
#include <hip/hip_bf16.h>

// GCN over Block-CSR adjacency. ALL I/O BUFFERS ARE FLOAT32 (reference dtypes).
// Compute: bf16 MFMA, fp32 accumulate; intermediates stored bf16.
//
// Pipeline: [gemm z=X@W -> z_bt layout] -> [spmm + bias + relu + LN -> h bf16 row-major] x2
//           -> [gemm z2=h@W2] -> [spmm + bias -> out f32]
// z_bt layout: per 16-row block rb, store [F][16] (feature-major, row-in-block innermost)
// so SpMM B-fragments (k-slices of gathered z rows) are contiguous 16B loads.
//
// d_ws: zbt + h (bf16) = exactly 128 MiB (= one f32 [N,256] intermediate's size).
// Transposed bf16 weights (229 KB) live in d_out-as-scratch (33.6 MB f32 buffer);
// consumed before spmm_out overwrites d_out (stream-ordered).

typedef __bf16 bf16;
typedef bf16 bf16x8 __attribute__((ext_vector_type(8)));
typedef bf16 bf16x4 __attribute__((ext_vector_type(4)));
typedef float f32x4 __attribute__((ext_vector_type(4)));

#define N_NODES 131072
#define BRQ 8192      // block rows (= N/16)
#define KNZ 8         // nonzero blocks per block row
#define IN_F 128
#define HID 256
#define NCLS 64

static __device__ __forceinline__ f32x4 mfma16(bf16x8 a, bf16x8 b, f32x4 c) {
  return __builtin_amdgcn_mfma_f32_16x16x32_bf16(a, b, c, 0, 0, 0);
}

// load 8 contiguous elements as a bf16x8 fragment (from bf16 or f32 memory)
static __device__ __forceinline__ bf16x8 load8(const bf16* p) {
  return *(const bf16x8*)p;
}
static __device__ __forceinline__ bf16x8 load8(const float* p) {
  f32x4 a0 = *(const f32x4*)p;
  f32x4 a1 = *(const f32x4*)(p + 4);
  bf16x8 r;
  r[0] = (bf16)a0[0]; r[1] = (bf16)a0[1]; r[2] = (bf16)a0[2]; r[3] = (bf16)a0[3];
  r[4] = (bf16)a1[0]; r[5] = (bf16)a1[1]; r[6] = (bf16)a1[2]; r[7] = (bf16)a1[3];
  return r;
}

// ---------------- transpose + f32->bf16 convert for W matrices (tiny) ------------
__global__ void transpose_cvt(const float* __restrict__ in, bf16* __restrict__ out,
                              int rows, int cols) {
  int idx = blockIdx.x * 256 + threadIdx.x;
  if (idx < rows * cols) {
    int r = idx / cols, c = idx - r * cols;
    out[c * rows + r] = (bf16)in[idx];
  }
}

// ---------------- dense GEMM: Zbt[rt][col][r] = X[N,KIN] @ W[KIN,FOUT] ------------
// WT is W transposed: [FOUT, KIN] row-major bf16. One wave computes a 16x64 tile.
// TA = float (layer 0 features) or bf16 (h from previous layer).
template<typename TA, int KIN, int FOUT>
__global__ __launch_bounds__(256) void gemm_bt(const TA* __restrict__ X,
                                               const bf16* __restrict__ WT,
                                               bf16* __restrict__ Zbt) {
  const int wave = threadIdx.x >> 6;
  const int lane = threadIdx.x & 63;
  const int l15  = lane & 15;
  const int quad = lane >> 4;
  const int CG   = FOUT / 64;               // 64-col groups
  const int gw   = blockIdx.x * 4 + wave;   // global wave id
  const int rt   = gw / CG;                 // 16-row tile index
  const int cg   = gw - rt * CG;

  const TA*   __restrict__ xrow  = X  + (long)(rt * 16 + l15) * KIN + quad * 8;
  const bf16* __restrict__ wbase = WT + (long)(cg * 64 + l15) * KIN + quad * 8;

  f32x4 acc[4] = {};
#pragma unroll
  for (int k0 = 0; k0 < KIN; k0 += 32) {
    bf16x8 a = load8(xrow + k0);
#pragma unroll
    for (int t = 0; t < 4; ++t) {
      bf16x8 b = *(const bf16x8*)(wbase + t * (16 * KIN) + k0);
      acc[t] = mfma16(a, b, acc[t]);
    }
  }
  // C/D: row = quad*4+i, col = t*16+l15. Store to Zbt[(rt*FOUT+col)*16 + row].
#pragma unroll
  for (int t = 0; t < 4; ++t) {
    int col = cg * 64 + t * 16 + l15;
    bf16* dst = Zbt + ((long)rt * FOUT + col) * 16 + quad * 4;
    bf16x4 v;
#pragma unroll
    for (int i = 0; i < 4; ++i) v[i] = (bf16)acc[t][i];
    *(bf16x4*)dst = v;
  }
}

// ---------------- SpMM + bias + ReLU + LayerNorm (F = HID = 256) -----------------
// One block per block-row; wave w covers cols [64w, 64w+64).
// K=8 blocks paired into 4 mfma K=32 steps:
//   quad 0: blk 2kp cols 0-7 | quad 1: blk 2kp cols 8-15
//   quad 2: blk 2kp+1 cols 0-7 | quad 3: blk 2kp+1 cols 8-15
__global__ __launch_bounds__(256) void spmm_ln(const float* __restrict__ Abv,
                                               const int*   __restrict__ Abc,
                                               const bf16*  __restrict__ Zbt,
                                               const float* __restrict__ bias,
                                               const float* __restrict__ gamma,
                                               const float* __restrict__ beta,
                                               bf16* __restrict__ H) {
  const int b    = blockIdx.x;
  const int wave = threadIdx.x >> 6;
  const int lane = threadIdx.x & 63;
  const int l15  = lane & 15;
  const int quad = lane >> 4;

  const int*   bc    = Abc + b * KNZ;
  const int    cst   = (quad & 1) * 8;
  const int    half  = quad >> 1;
  const float* abase = Abv + (long)b * (KNZ * 256) + l15 * 16 + cst;

  f32x4 acc[4] = {};
#pragma unroll
  for (int kp = 0; kp < 4; ++kp) {
    int blk = 2 * kp + half;
    bf16x8 a = load8(abase + blk * 256);
    long zb = (long)bc[blk] * (HID * 16) + cst;
#pragma unroll
    for (int t = 0; t < 4; ++t) {
      int f = wave * 64 + t * 16 + l15;
      bf16x8 bb = *(const bf16x8*)(Zbt + zb + f * 16);
      acc[t] = mfma16(a, bb, acc[t]);
    }
  }

  // bias + relu into LDS, then per-row LayerNorm
  __shared__ float ld[16][257];
#pragma unroll
  for (int t = 0; t < 4; ++t) {
    int f = wave * 64 + t * 16 + l15;
    float bi = bias[f];
#pragma unroll
    for (int i = 0; i < 4; ++i) {
      float v = acc[t][i] + bi;
      ld[quad * 4 + i][f] = v > 0.f ? v : 0.f;
    }
  }
  __syncthreads();

  // wave w normalizes rows 4w..4w+3; lane covers cols {lane, lane+64, lane+128, lane+192}
#pragma unroll
  for (int rr = 0; rr < 4; ++rr) {
    int r = wave * 4 + rr;
    float v0 = ld[r][lane], v1 = ld[r][64 + lane];
    float v2 = ld[r][128 + lane], v3 = ld[r][192 + lane];
    float s  = v0 + v1 + v2 + v3;
    float ss = v0 * v0 + v1 * v1 + v2 * v2 + v3 * v3;
#pragma unroll
    for (int m = 1; m < 64; m <<= 1) {
      s  += __shfl_xor(s, m, 64);
      ss += __shfl_xor(ss, m, 64);
    }
    float mu   = s * (1.f / 256.f);
    float var  = ss * (1.f / 256.f) - mu * mu;
    float rstd = rsqrtf(var + 1e-5f);
    bf16* hrow = H + (long)(b * 16 + r) * HID;
    float vv[4] = {v0, v1, v2, v3};
#pragma unroll
    for (int k2 = 0; k2 < 4; ++k2) {
      int f = k2 * 64 + lane;
      float y = (vv[k2] - mu) * rstd * gamma[f] + beta[f];
      hrow[f] = (bf16)y;
    }
  }
}

// ---------------- final SpMM + bias (F = NCLS = 64), row-major FLOAT32 out -------
__global__ __launch_bounds__(256) void spmm_out(const float* __restrict__ Abv,
                                                const int*   __restrict__ Abc,
                                                const bf16*  __restrict__ Zbt,  // [BRQ,64,16]
                                                const float* __restrict__ bias, // [64]
                                                float* __restrict__ out) {      // [N,64] f32
  const int wave = threadIdx.x >> 6;
  const int b    = blockIdx.x * 4 + wave;   // one block-row per wave
  const int lane = threadIdx.x & 63;
  const int l15  = lane & 15;
  const int quad = lane >> 4;

  const int*   bc    = Abc + b * KNZ;
  const int    cst   = (quad & 1) * 8;
  const int    half  = quad >> 1;
  const float* abase = Abv + (long)b * (KNZ * 256) + l15 * 16 + cst;

  f32x4 acc[4] = {};
#pragma unroll
  for (int kp = 0; kp < 4; ++kp) {
    int blk = 2 * kp + half;
    bf16x8 a = load8(abase + blk * 256);
    long zb = (long)bc[blk] * (NCLS * 16) + cst;
#pragma unroll
    for (int t = 0; t < 4; ++t) {
      int f = t * 16 + l15;
      bf16x8 bb = *(const bf16x8*)(Zbt + zb + f * 16);
      acc[t] = mfma16(a, bb, acc[t]);
    }
  }
#pragma unroll
  for (int t = 0; t < 4; ++t) {
    int f = t * 16 + l15;
    float bi = bias[f];
#pragma unroll
    for (int i = 0; i < 4; ++i) {
      out[(long)(b * 16 + quad * 4 + i) * NCLS + f] = acc[t][i] + bi;
    }
  }
}

extern "C" void kernel_launch(void* const* d_in, const int* in_sizes, int n_in,
                              void* d_out, int out_size, void* d_ws, size_t ws_size,
                              hipStream_t stream) {
  const float* features = (const float*)d_in[0];
  const float* bvals    = (const float*)d_in[1];
  const float* W0       = (const float*)d_in[2];
  const float* b0       = (const float*)d_in[3];
  const float* W1       = (const float*)d_in[4];
  const float* b1       = (const float*)d_in[5];
  const float* W2       = (const float*)d_in[6];
  const float* b2       = (const float*)d_in[7];
  const float* g0       = (const float*)d_in[8];
  const float* beta0    = (const float*)d_in[9];
  const float* g1       = (const float*)d_in[10];
  const float* beta1    = (const float*)d_in[11];
  const int*   bcols    = (const int*)d_in[12];
  float* outp = (float*)d_out;

  // d_ws: zbt [N*HID] + h [N*HID] bf16 = exactly 128 MiB (= one f32 [N,256]).
  bf16* zbt = (bf16*)d_ws;
  bf16* h   = zbt + (size_t)N_NODES * HID;

  // Transposed bf16 weights in d_out-as-scratch (229 KB of the 33.6 MB f32 output
  // buffer). All reads complete before spmm_out overwrites d_out (stream order).
  bf16* w0t = (bf16*)d_out;         // IN_F*HID  = 32768 elems
  bf16* w1t = w0t + IN_F * HID;     // HID*HID   = 65536 elems
  bf16* w2t = w1t + HID * HID;      // HID*NCLS  = 16384 elems  (114688 bf16 = 229 KB)

  transpose_cvt<<<dim3((IN_F * HID + 255) / 256), dim3(256), 0, stream>>>(W0, w0t, IN_F, HID);
  transpose_cvt<<<dim3((HID * HID + 255) / 256), dim3(256), 0, stream>>>(W1, w1t, HID, HID);
  transpose_cvt<<<dim3((HID * NCLS + 255) / 256), dim3(256), 0, stream>>>(W2, w2t, HID, NCLS);

  // layer 0
  gemm_bt<float, IN_F, HID><<<dim3(BRQ), dim3(256), 0, stream>>>(features, w0t, zbt);
  spmm_ln<<<dim3(BRQ), dim3(256), 0, stream>>>(bvals, bcols, zbt, b0, g0, beta0, h);
  // layer 1
  gemm_bt<bf16, HID, HID><<<dim3(BRQ), dim3(256), 0, stream>>>(h, w1t, zbt);
  spmm_ln<<<dim3(BRQ), dim3(256), 0, stream>>>(bvals, bcols, zbt, b1, g1, beta1, h);
  // output layer
  gemm_bt<bf16, HID, NCLS><<<dim3(BRQ / 4), dim3(256), 0, stream>>>(h, w2t, zbt);
  spmm_out<<<dim3(BRQ / 4), dim3(256), 0, stream>>>(bvals, bcols, zbt, b2, outp);
}

// Round 5
// 466.083 us; speedup vs baseline: 1.3348x; 1.3348x over previous
//
#include <hip/hip_runtime.h>
#include <hip/hip_bf16.h>

// GCN over Block-CSR adjacency. ALL I/O BUFFERS ARE FLOAT32 (reference dtypes).
// Compute: bf16 MFMA, fp32 accumulate; intermediates stored bf16.
//
// Round 5: attack latency-boundedness (R4 counters: MfmaUtil 4.4%, VALUBusy 3.5%,
// HBM 8.3% on the dominant GEMM => load-latency bound).
//  - gemm_bt v2: B-stationary in registers (64 cols x full K = 128 VGPR), grid-strided
//    row-tiles with double-buffered A prefetch. Load:MFMA 8:32 per tile.
//  - spmm v2: preload ALL A-frags + ALL 16 gathered B-frags before first MFMA
//    (20 loads in flight vs ~2).
//
// z_bt layout: per 16-row block rb, store [F][16] so SpMM B-fragments are 16B loads.
// d_ws: zbt + h (bf16) = exactly 128 MiB. Transposed bf16 weights (229 KB) in
// d_out-as-scratch; consumed before spmm_out overwrites d_out (stream-ordered).

typedef __bf16 bf16;
typedef bf16 bf16x8 __attribute__((ext_vector_type(8)));
typedef bf16 bf16x4 __attribute__((ext_vector_type(4)));
typedef float f32x4 __attribute__((ext_vector_type(4)));

#define N_NODES 131072
#define BRQ 8192      // block rows (= N/16)
#define KNZ 8         // nonzero blocks per block row
#define IN_F 128
#define HID 256
#define NCLS 64

static __device__ __forceinline__ f32x4 mfma16(bf16x8 a, bf16x8 b, f32x4 c) {
  return __builtin_amdgcn_mfma_f32_16x16x32_bf16(a, b, c, 0, 0, 0);
}

static __device__ __forceinline__ bf16x8 load8(const bf16* p) {
  return *(const bf16x8*)p;
}
static __device__ __forceinline__ bf16x8 load8(const float* p) {
  f32x4 a0 = *(const f32x4*)p;
  f32x4 a1 = *(const f32x4*)(p + 4);
  bf16x8 r;
  r[0] = (bf16)a0[0]; r[1] = (bf16)a0[1]; r[2] = (bf16)a0[2]; r[3] = (bf16)a0[3];
  r[4] = (bf16)a1[0]; r[5] = (bf16)a1[1]; r[6] = (bf16)a1[2]; r[7] = (bf16)a1[3];
  return r;
}

// ---------------- transpose + f32->bf16 convert for W matrices (tiny) ------------
__global__ void transpose_cvt(const float* __restrict__ in, bf16* __restrict__ out,
                              int rows, int cols) {
  int idx = blockIdx.x * 256 + threadIdx.x;
  if (idx < rows * cols) {
    int r = idx / cols, c = idx - r * cols;
    out[c * rows + r] = (bf16)in[idx];
  }
}

// ---------------- dense GEMM v2: B-stationary registers ---------------------------
// Zbt[rt][col][r] = X[N,KIN] @ W[KIN,FOUT]; WT = W^T [FOUT,KIN] bf16 row-major.
// Wave holds its 64-col slab of WT over the whole K in registers (KIN/32*4 bf16x8),
// then sweeps row-tiles rt (grid-strided) with double-buffered A prefetch.
template<typename TA, int KIN, int FOUT, int GRID>
__global__ __launch_bounds__(256) void gemm_bt(const TA* __restrict__ X,
                                               const bf16* __restrict__ WT,
                                               bf16* __restrict__ Zbt) {
  constexpr int CG  = FOUT / 64;          // 64-col groups
  constexpr int KS  = KIN / 32;           // K steps
  constexpr int RTS = GRID * 4 / CG;      // row-tile stride (waves per col group)
  constexpr int NT  = BRQ / RTS;          // row-tiles per wave (8192/1024=8, /2048=4)

  const int wave = threadIdx.x >> 6;
  const int lane = threadIdx.x & 63;
  const int l15  = lane & 15;
  const int quad = lane >> 4;
  const int gw   = blockIdx.x * 4 + wave;
  const int cg   = gw % CG;
  const int rt0  = gw / CG;

  // B preload: [k][t] fragments, stays in VGPRs for the whole kernel.
  const bf16* __restrict__ wbase = WT + (long)(cg * 64 + l15) * KIN + quad * 8;
  bf16x8 bfr[KS][4];
#pragma unroll
  for (int k = 0; k < KS; ++k)
#pragma unroll
    for (int t = 0; t < 4; ++t)
      bfr[k][t] = *(const bf16x8*)(wbase + t * (16 * KIN) + k * 32);

  const TA* __restrict__ xbase = X + (long)l15 * KIN + quad * 8;

  bf16x8 aw[2][KS];
#pragma unroll
  for (int k = 0; k < KS; ++k)
    aw[0][k] = load8(xbase + (long)rt0 * (16 * KIN) + k * 32);

#pragma unroll
  for (int it = 0; it < NT; ++it) {
    const int rt = rt0 + it * RTS;
    if (it + 1 < NT) {
      const long xoff = (long)(rt + RTS) * (16 * KIN);
#pragma unroll
      for (int k = 0; k < KS; ++k)
        aw[(it + 1) & 1][k] = load8(xbase + xoff + k * 32);
    }
    f32x4 acc[4] = {};
#pragma unroll
    for (int k = 0; k < KS; ++k)
#pragma unroll
      for (int t = 0; t < 4; ++t)
        acc[t] = mfma16(aw[it & 1][k], bfr[k][t], acc[t]);
    // C/D: row = quad*4+i, col = cg*64 + t*16 + l15 -> Zbt[(rt*FOUT+col)*16 + row]
#pragma unroll
    for (int t = 0; t < 4; ++t) {
      int col = cg * 64 + t * 16 + l15;
      bf16x4 v;
#pragma unroll
      for (int i = 0; i < 4; ++i) v[i] = (bf16)acc[t][i];
      *(bf16x4*)(Zbt + ((long)rt * FOUT + col) * 16 + quad * 4) = v;
    }
  }
}

// ---------------- SpMM + bias + ReLU + LayerNorm (F = HID = 256) -----------------
// One block per block-row; wave w covers cols [64w, 64w+64).
// All 4 A-fragments and all 16 gathered B-fragments are loaded BEFORE the MFMAs.
__global__ __launch_bounds__(256) void spmm_ln(const float* __restrict__ Abv,
                                               const int*   __restrict__ Abc,
                                               const bf16*  __restrict__ Zbt,
                                               const float* __restrict__ bias,
                                               const float* __restrict__ gamma,
                                               const float* __restrict__ beta,
                                               bf16* __restrict__ H) {
  const int b    = blockIdx.x;
  const int wave = threadIdx.x >> 6;
  const int lane = threadIdx.x & 63;
  const int l15  = lane & 15;
  const int quad = lane >> 4;

  const int*   bc    = Abc + b * KNZ;
  const int    cst   = (quad & 1) * 8;
  const int    half  = quad >> 1;
  const float* abase = Abv + (long)b * (KNZ * 256) + l15 * 16 + cst;

  bf16x8 afr[4];
  long   zb[4];
#pragma unroll
  for (int kp = 0; kp < 4; ++kp) {
    int blk = 2 * kp + half;
    afr[kp] = load8(abase + blk * 256);
    zb[kp]  = (long)bc[blk] * (HID * 16) + cst;
  }
  bf16x8 bfr[4][4];
#pragma unroll
  for (int kp = 0; kp < 4; ++kp)
#pragma unroll
    for (int t = 0; t < 4; ++t) {
      int f = wave * 64 + t * 16 + l15;
      bfr[kp][t] = *(const bf16x8*)(Zbt + zb[kp] + f * 16);
    }

  f32x4 acc[4] = {};
#pragma unroll
  for (int kp = 0; kp < 4; ++kp)
#pragma unroll
    for (int t = 0; t < 4; ++t)
      acc[t] = mfma16(afr[kp], bfr[kp][t], acc[t]);

  // bias + relu into LDS, then per-row LayerNorm
  __shared__ float ld[16][257];
#pragma unroll
  for (int t = 0; t < 4; ++t) {
    int f = wave * 64 + t * 16 + l15;
    float bi = bias[f];
#pragma unroll
    for (int i = 0; i < 4; ++i) {
      float v = acc[t][i] + bi;
      ld[quad * 4 + i][f] = v > 0.f ? v : 0.f;
    }
  }
  __syncthreads();

  // wave w normalizes rows 4w..4w+3; lane covers cols {lane, +64, +128, +192}
#pragma unroll
  for (int rr = 0; rr < 4; ++rr) {
    int r = wave * 4 + rr;
    float v0 = ld[r][lane], v1 = ld[r][64 + lane];
    float v2 = ld[r][128 + lane], v3 = ld[r][192 + lane];
    float s  = v0 + v1 + v2 + v3;
    float ss = v0 * v0 + v1 * v1 + v2 * v2 + v3 * v3;
#pragma unroll
    for (int m = 1; m < 64; m <<= 1) {
      s  += __shfl_xor(s, m, 64);
      ss += __shfl_xor(ss, m, 64);
    }
    float mu   = s * (1.f / 256.f);
    float var  = ss * (1.f / 256.f) - mu * mu;
    float rstd = rsqrtf(var + 1e-5f);
    bf16* hrow = H + (long)(b * 16 + r) * HID;
    float vv[4] = {v0, v1, v2, v3};
#pragma unroll
    for (int k2 = 0; k2 < 4; ++k2) {
      int f = k2 * 64 + lane;
      float y = (vv[k2] - mu) * rstd * gamma[f] + beta[f];
      hrow[f] = (bf16)y;
    }
  }
}

// ---------------- final SpMM + bias (F = NCLS = 64), row-major FLOAT32 out -------
__global__ __launch_bounds__(256) void spmm_out(const float* __restrict__ Abv,
                                                const int*   __restrict__ Abc,
                                                const bf16*  __restrict__ Zbt,  // [BRQ,64,16]
                                                const float* __restrict__ bias, // [64]
                                                float* __restrict__ out) {      // [N,64] f32
  const int wave = threadIdx.x >> 6;
  const int b    = blockIdx.x * 4 + wave;   // one block-row per wave
  const int lane = threadIdx.x & 63;
  const int l15  = lane & 15;
  const int quad = lane >> 4;

  const int*   bc    = Abc + b * KNZ;
  const int    cst   = (quad & 1) * 8;
  const int    half  = quad >> 1;
  const float* abase = Abv + (long)b * (KNZ * 256) + l15 * 16 + cst;

  bf16x8 afr[4];
  long   zb[4];
#pragma unroll
  for (int kp = 0; kp < 4; ++kp) {
    int blk = 2 * kp + half;
    afr[kp] = load8(abase + blk * 256);
    zb[kp]  = (long)bc[blk] * (NCLS * 16) + cst;
  }
  bf16x8 bfr[4][4];
#pragma unroll
  for (int kp = 0; kp < 4; ++kp)
#pragma unroll
    for (int t = 0; t < 4; ++t) {
      int f = t * 16 + l15;
      bfr[kp][t] = *(const bf16x8*)(Zbt + zb[kp] + f * 16);
    }

  f32x4 acc[4] = {};
#pragma unroll
  for (int kp = 0; kp < 4; ++kp)
#pragma unroll
    for (int t = 0; t < 4; ++t)
      acc[t] = mfma16(afr[kp], bfr[kp][t], acc[t]);

#pragma unroll
  for (int t = 0; t < 4; ++t) {
    int f = t * 16 + l15;
    float bi = bias[f];
#pragma unroll
    for (int i = 0; i < 4; ++i) {
      out[(long)(b * 16 + quad * 4 + i) * NCLS + f] = acc[t][i] + bi;
    }
  }
}

extern "C" void kernel_launch(void* const* d_in, const int* in_sizes, int n_in,
                              void* d_out, int out_size, void* d_ws, size_t ws_size,
                              hipStream_t stream) {
  const float* features = (const float*)d_in[0];
  const float* bvals    = (const float*)d_in[1];
  const float* W0       = (const float*)d_in[2];
  const float* b0       = (const float*)d_in[3];
  const float* W1       = (const float*)d_in[4];
  const float* b1       = (const float*)d_in[5];
  const float* W2       = (const float*)d_in[6];
  const float* b2       = (const float*)d_in[7];
  const float* g0       = (const float*)d_in[8];
  const float* beta0    = (const float*)d_in[9];
  const float* g1       = (const float*)d_in[10];
  const float* beta1    = (const float*)d_in[11];
  const int*   bcols    = (const int*)d_in[12];
  float* outp = (float*)d_out;

  // d_ws: zbt [N*HID] + h [N*HID] bf16 = exactly 128 MiB.
  bf16* zbt = (bf16*)d_ws;
  bf16* h   = zbt + (size_t)N_NODES * HID;

  // Transposed bf16 weights in d_out-as-scratch (229 KB of the 33.6 MB f32 output
  // buffer). All reads complete before spmm_out overwrites d_out (stream order).
  bf16* w0t = (bf16*)d_out;         // IN_F*HID  = 32768 elems
  bf16* w1t = w0t + IN_F * HID;     // HID*HID   = 65536 elems
  bf16* w2t = w1t + HID * HID;      // HID*NCLS  = 16384 elems

  transpose_cvt<<<dim3((IN_F * HID + 255) / 256), dim3(256), 0, stream>>>(W0, w0t, IN_F, HID);
  transpose_cvt<<<dim3((HID * HID + 255) / 256), dim3(256), 0, stream>>>(W1, w1t, HID, HID);
  transpose_cvt<<<dim3((HID * NCLS + 255) / 256), dim3(256), 0, stream>>>(W2, w2t, HID, NCLS);

  // layer 0: 1024 blocks, CG=4 -> 8 row-tiles/wave
  gemm_bt<float, IN_F, HID, 1024><<<dim3(1024), dim3(256), 0, stream>>>(features, w0t, zbt);
  spmm_ln<<<dim3(BRQ), dim3(256), 0, stream>>>(bvals, bcols, zbt, b0, g0, beta0, h);
  // layer 1
  gemm_bt<bf16, HID, HID, 1024><<<dim3(1024), dim3(256), 0, stream>>>(h, w1t, zbt);
  spmm_ln<<<dim3(BRQ), dim3(256), 0, stream>>>(bvals, bcols, zbt, b1, g1, beta1, h);
  // output layer: CG=1, 512 blocks -> 4 row-tiles/wave
  gemm_bt<bf16, HID, NCLS, 512><<<dim3(512), dim3(256), 0, stream>>>(h, w2t, zbt);
  spmm_out<<<dim3(BRQ / 4), dim3(256), 0, stream>>>(bvals, bcols, zbt, b2, outp);
}

// Round 6
// 464.533 us; speedup vs baseline: 1.3392x; 1.0033x over previous
//
#include <hip/hip_runtime.h>
#include <hip/hip_bf16.h>

// GCN over Block-CSR adjacency. ALL I/O BUFFERS ARE FLOAT32 (reference dtypes).
// Compute: bf16 MFMA, fp32 accumulate; intermediates stored bf16.
//
// Round 6: spmm_ln v3 (evidence: R5 counters VGPR=52 -> compiler sank gather loads,
// MLP-starved at 48% HBM; 16KB LDS LN roundtrip + 1M bank-conflict cycles).
//  - one wave per 128-col half of a block-row: 36 gathers with overlapping live
//    ranges (~200 VGPR) => loads stay in flight.
//  - LayerNorm from accumulators: shuffle-reduce + 512B LDS partial-sum exchange.
//  - 3 transpose kernels fused into 1.
//
// z_bt layout: per 16-row block rb, store [F][16] so SpMM B-fragments are 16B loads.
// d_ws: zbt + h (bf16) = exactly 128 MiB. Transposed bf16 weights (229 KB) in
// d_out-as-scratch; consumed before spmm_out overwrites d_out (stream-ordered).

typedef __bf16 bf16;
typedef bf16 bf16x8 __attribute__((ext_vector_type(8)));
typedef bf16 bf16x4 __attribute__((ext_vector_type(4)));
typedef float f32x4 __attribute__((ext_vector_type(4)));

#define N_NODES 131072
#define BRQ 8192      // block rows (= N/16)
#define KNZ 8         // nonzero blocks per block row
#define IN_F 128
#define HID 256
#define NCLS 64

static __device__ __forceinline__ f32x4 mfma16(bf16x8 a, bf16x8 b, f32x4 c) {
  return __builtin_amdgcn_mfma_f32_16x16x32_bf16(a, b, c, 0, 0, 0);
}

static __device__ __forceinline__ bf16x8 load8(const bf16* p) {
  return *(const bf16x8*)p;
}
static __device__ __forceinline__ bf16x8 load8(const float* p) {
  f32x4 a0 = *(const f32x4*)p;
  f32x4 a1 = *(const f32x4*)(p + 4);
  bf16x8 r;
  r[0] = (bf16)a0[0]; r[1] = (bf16)a0[1]; r[2] = (bf16)a0[2]; r[3] = (bf16)a0[3];
  r[4] = (bf16)a1[0]; r[5] = (bf16)a1[1]; r[6] = (bf16)a1[2]; r[7] = (bf16)a1[3];
  return r;
}

// ---------------- fused transpose + f32->bf16 convert for all 3 W matrices -------
// sizes: W0 128x256 (32768), W1 256x256 (65536), W2 256x64 (16384) => 114688 elems
__global__ void transpose_all(const float* __restrict__ W0, const float* __restrict__ W1,
                              const float* __restrict__ W2, bf16* __restrict__ w0t,
                              bf16* __restrict__ w1t, bf16* __restrict__ w2t) {
  int idx = blockIdx.x * 256 + threadIdx.x;
  if (idx < 32768) {
    int r = idx >> 8, c = idx & 255;            // 128 x 256
    w0t[c * 128 + r] = (bf16)W0[idx];
  } else if (idx < 98304) {
    int j = idx - 32768; int r = j >> 8, c = j & 255;  // 256 x 256
    w1t[c * 256 + r] = (bf16)W1[j];
  } else {
    int j = idx - 98304; int r = j >> 6, c = j & 63;   // 256 x 64
    w2t[c * 256 + r] = (bf16)W2[j];
  }
}

// ---------------- dense GEMM: B-stationary registers ------------------------------
// Zbt[rt][col][r] = X[N,KIN] @ W[KIN,FOUT]; WT = W^T [FOUT,KIN] bf16 row-major.
template<typename TA, int KIN, int FOUT, int GRID>
__global__ __launch_bounds__(256) void gemm_bt(const TA* __restrict__ X,
                                               const bf16* __restrict__ WT,
                                               bf16* __restrict__ Zbt) {
  constexpr int CG  = FOUT / 64;          // 64-col groups
  constexpr int KS  = KIN / 32;           // K steps
  constexpr int RTS = GRID * 4 / CG;      // row-tile stride (waves per col group)
  constexpr int NT  = BRQ / RTS;          // row-tiles per wave

  const int wave = threadIdx.x >> 6;
  const int lane = threadIdx.x & 63;
  const int l15  = lane & 15;
  const int quad = lane >> 4;
  const int gw   = blockIdx.x * 4 + wave;
  const int cg   = gw % CG;
  const int rt0  = gw / CG;

  const bf16* __restrict__ wbase = WT + (long)(cg * 64 + l15) * KIN + quad * 8;
  bf16x8 bfr[KS][4];
#pragma unroll
  for (int k = 0; k < KS; ++k)
#pragma unroll
    for (int t = 0; t < 4; ++t)
      bfr[k][t] = *(const bf16x8*)(wbase + t * (16 * KIN) + k * 32);

  const TA* __restrict__ xbase = X + (long)l15 * KIN + quad * 8;

  bf16x8 aw[2][KS];
#pragma unroll
  for (int k = 0; k < KS; ++k)
    aw[0][k] = load8(xbase + (long)rt0 * (16 * KIN) + k * 32);

#pragma unroll
  for (int it = 0; it < NT; ++it) {
    const int rt = rt0 + it * RTS;
    if (it + 1 < NT) {
      const long xoff = (long)(rt + RTS) * (16 * KIN);
#pragma unroll
      for (int k = 0; k < KS; ++k)
        aw[(it + 1) & 1][k] = load8(xbase + xoff + k * 32);
    }
    f32x4 acc[4] = {};
#pragma unroll
    for (int k = 0; k < KS; ++k)
#pragma unroll
      for (int t = 0; t < 4; ++t)
        acc[t] = mfma16(aw[it & 1][k], bfr[k][t], acc[t]);
#pragma unroll
    for (int t = 0; t < 4; ++t) {
      int col = cg * 64 + t * 16 + l15;
      bf16x4 v;
#pragma unroll
      for (int i = 0; i < 4; ++i) v[i] = (bf16)acc[t][i];
      *(bf16x4*)(Zbt + ((long)rt * FOUT + col) * 16 + quad * 4) = v;
    }
  }
}

// ---------------- SpMM + bias + ReLU + LayerNorm (F = HID = 256) v3 ---------------
// Block = 4 waves = 2 block-rows. Wave (pair,ch): block-row b = blockIdx*2 + pair,
// columns [ch*128, ch*128+128). 4 A-frags + 32 gathered B-frags per wave, all live
// before the MFMA chain. LN: per-lane partials -> 16-lane shuffle reduce ->
// 512B LDS exchange between the two column halves -> normalize from registers.
__global__ __launch_bounds__(256) void spmm_ln(const float* __restrict__ Abv,
                                               const int*   __restrict__ Abc,
                                               const bf16*  __restrict__ Zbt,
                                               const float* __restrict__ bias,
                                               const float* __restrict__ gamma,
                                               const float* __restrict__ beta,
                                               bf16* __restrict__ H) {
  const int wave = threadIdx.x >> 6;
  const int lane = threadIdx.x & 63;
  const int l15  = lane & 15;
  const int quad = lane >> 4;
  const int b    = blockIdx.x * 2 + (wave >> 1);
  const int ch   = wave & 1;               // column half

  const int*   bc    = Abc + b * KNZ;
  const int    cst   = (quad & 1) * 8;
  const int    half  = quad >> 1;
  const float* abase = Abv + (long)b * (KNZ * 256) + l15 * 16 + cst;

  bf16x8 afr[4];
  long   zb[4];
#pragma unroll
  for (int kp = 0; kp < 4; ++kp) {
    int blk = 2 * kp + half;
    afr[kp] = load8(abase + blk * 256);
    zb[kp]  = (long)bc[blk] * (HID * 16) + cst;
  }
  bf16x8 bfr[4][8];
#pragma unroll
  for (int kp = 0; kp < 4; ++kp)
#pragma unroll
    for (int t = 0; t < 8; ++t) {
      int f = ch * 128 + t * 16 + l15;
      bfr[kp][t] = *(const bf16x8*)(Zbt + zb[kp] + f * 16);
    }

  f32x4 acc[8] = {};
#pragma unroll
  for (int kp = 0; kp < 4; ++kp)
#pragma unroll
    for (int t = 0; t < 8; ++t)
      acc[t] = mfma16(afr[kp], bfr[kp][t], acc[t]);

  // bias + relu in-register, accumulate per-row partial sums
  float gv[8], bv[8];
#pragma unroll
  for (int t = 0; t < 8; ++t) {
    int f = ch * 128 + t * 16 + l15;
    gv[t] = gamma[f];
    bv[t] = beta[f];
  }
  float ps[4] = {0.f, 0.f, 0.f, 0.f}, pss[4] = {0.f, 0.f, 0.f, 0.f};
#pragma unroll
  for (int t = 0; t < 8; ++t) {
    float bi = bias[ch * 128 + t * 16 + l15];
#pragma unroll
    for (int i = 0; i < 4; ++i) {
      float v = acc[t][i] + bi;
      v = v > 0.f ? v : 0.f;
      acc[t][i] = v;
      ps[i] += v;
      pss[i] += v * v;
    }
  }
  // reduce across the 16 lanes of this quad (rows quad*4+i)
#pragma unroll
  for (int m = 1; m < 16; m <<= 1) {
#pragma unroll
    for (int i = 0; i < 4; ++i) {
      ps[i]  += __shfl_xor(ps[i], m, 64);
      pss[i] += __shfl_xor(pss[i], m, 64);
    }
  }
  // exchange the two 128-col halves via tiny LDS
  __shared__ float S[4][16], SS[4][16];
  if (l15 == 0) {
#pragma unroll
    for (int i = 0; i < 4; ++i) {
      S[wave][quad * 4 + i]  = ps[i];
      SS[wave][quad * 4 + i] = pss[i];
    }
  }
  __syncthreads();
#pragma unroll
  for (int i = 0; i < 4; ++i) {
    int r = quad * 4 + i;
    float s    = S[wave][r] + S[wave ^ 1][r];
    float ss   = SS[wave][r] + SS[wave ^ 1][r];
    float mu   = s * (1.f / 256.f);
    float var  = ss * (1.f / 256.f) - mu * mu;
    float rstd = rsqrtf(var + 1e-5f);
    bf16* hrow = H + (long)(b * 16 + r) * HID;
#pragma unroll
    for (int t = 0; t < 8; ++t) {
      int f = ch * 128 + t * 16 + l15;
      float y = (acc[t][i] - mu) * rstd * gv[t] + bv[t];
      hrow[f] = (bf16)y;
    }
  }
}

// ---------------- final SpMM + bias (F = NCLS = 64), row-major FLOAT32 out -------
__global__ __launch_bounds__(256) void spmm_out(const float* __restrict__ Abv,
                                                const int*   __restrict__ Abc,
                                                const bf16*  __restrict__ Zbt,  // [BRQ,64,16]
                                                const float* __restrict__ bias, // [64]
                                                float* __restrict__ out) {      // [N,64] f32
  const int wave = threadIdx.x >> 6;
  const int b    = blockIdx.x * 4 + wave;   // one block-row per wave
  const int lane = threadIdx.x & 63;
  const int l15  = lane & 15;
  const int quad = lane >> 4;

  const int*   bc    = Abc + b * KNZ;
  const int    cst   = (quad & 1) * 8;
  const int    half  = quad >> 1;
  const float* abase = Abv + (long)b * (KNZ * 256) + l15 * 16 + cst;

  bf16x8 afr[4];
  long   zb[4];
#pragma unroll
  for (int kp = 0; kp < 4; ++kp) {
    int blk = 2 * kp + half;
    afr[kp] = load8(abase + blk * 256);
    zb[kp]  = (long)bc[blk] * (NCLS * 16) + cst;
  }
  bf16x8 bfr[4][4];
#pragma unroll
  for (int kp = 0; kp < 4; ++kp)
#pragma unroll
    for (int t = 0; t < 4; ++t) {
      int f = t * 16 + l15;
      bfr[kp][t] = *(const bf16x8*)(Zbt + zb[kp] + f * 16);
    }

  f32x4 acc[4] = {};
#pragma unroll
  for (int kp = 0; kp < 4; ++kp)
#pragma unroll
    for (int t = 0; t < 4; ++t)
      acc[t] = mfma16(afr[kp], bfr[kp][t], acc[t]);

#pragma unroll
  for (int t = 0; t < 4; ++t) {
    int f = t * 16 + l15;
    float bi = bias[f];
#pragma unroll
    for (int i = 0; i < 4; ++i) {
      out[(long)(b * 16 + quad * 4 + i) * NCLS + f] = acc[t][i] + bi;
    }
  }
}

extern "C" void kernel_launch(void* const* d_in, const int* in_sizes, int n_in,
                              void* d_out, int out_size, void* d_ws, size_t ws_size,
                              hipStream_t stream) {
  const float* features = (const float*)d_in[0];
  const float* bvals    = (const float*)d_in[1];
  const float* W0       = (const float*)d_in[2];
  const float* b0       = (const float*)d_in[3];
  const float* W1       = (const float*)d_in[4];
  const float* b1       = (const float*)d_in[5];
  const float* W2       = (const float*)d_in[6];
  const float* b2       = (const float*)d_in[7];
  const float* g0       = (const float*)d_in[8];
  const float* beta0    = (const float*)d_in[9];
  const float* g1       = (const float*)d_in[10];
  const float* beta1    = (const float*)d_in[11];
  const int*   bcols    = (const int*)d_in[12];
  float* outp = (float*)d_out;

  // d_ws: zbt [N*HID] + h [N*HID] bf16 = exactly 128 MiB.
  bf16* zbt = (bf16*)d_ws;
  bf16* h   = zbt + (size_t)N_NODES * HID;

  // Transposed bf16 weights in d_out-as-scratch (229 KB of the 33.6 MB f32 output
  // buffer). All reads complete before spmm_out overwrites d_out (stream order).
  bf16* w0t = (bf16*)d_out;         // IN_F*HID  = 32768 elems
  bf16* w1t = w0t + IN_F * HID;     // HID*HID   = 65536 elems
  bf16* w2t = w1t + HID * HID;      // HID*NCLS  = 16384 elems

  transpose_all<<<dim3(448), dim3(256), 0, stream>>>(W0, W1, W2, w0t, w1t, w2t);

  // layer 0: 1024 blocks, CG=4 -> 8 row-tiles/wave
  gemm_bt<float, IN_F, HID, 1024><<<dim3(1024), dim3(256), 0, stream>>>(features, w0t, zbt);
  spmm_ln<<<dim3(BRQ / 2), dim3(256), 0, stream>>>(bvals, bcols, zbt, b0, g0, beta0, h);
  // layer 1
  gemm_bt<bf16, HID, HID, 1024><<<dim3(1024), dim3(256), 0, stream>>>(h, w1t, zbt);
  spmm_ln<<<dim3(BRQ / 2), dim3(256), 0, stream>>>(bvals, bcols, zbt, b1, g1, beta1, h);
  // output layer: CG=1, 512 blocks -> 4 row-tiles/wave
  gemm_bt<bf16, HID, NCLS, 512><<<dim3(512), dim3(256), 0, stream>>>(h, w2t, zbt);
  spmm_out<<<dim3(BRQ / 4), dim3(256), 0, stream>>>(bvals, bcols, zbt, b2, outp);
}